// Round 1
// baseline (11353.410 us; speedup 1.0000x reference)
//
#include <hip/hip_runtime.h>

#define NN 100000
#define EE 1600000
#define CC 128
#define EPS 1e-5f

// ---------- degree count (once per launch) ----------
__global__ __launch_bounds__(256) void k_count(const int* __restrict__ ei,
                                               float* __restrict__ cnt) {
    int e = blockIdx.x * 256 + threadIdx.x;
    if (e < EE) atomicAdd(&cnt[ei[EE + e]], 1.0f);
}

__global__ __launch_bounds__(256) void k_inv(const float* __restrict__ cnt,
                                             float* __restrict__ inv) {
    int n = blockIdx.x * 256 + threadIdx.x;
    if (n < NN) inv[n] = 1.0f / fmaxf(cnt[n], 1.0f);
}

// ---------- scatter-add: 32 threads per edge, float4 per thread ----------
__global__ __launch_bounds__(256) void k_scatter(const int* __restrict__ ei,
                                                 const float* __restrict__ h,
                                                 float* __restrict__ agg) {
    unsigned gid = blockIdx.x * 256u + threadIdx.x;
    int e = gid >> 5;
    int q = (gid & 31) << 2;
    int s = ei[e];
    int d = ei[EE + e];
    float4 v = *(const float4*)(h + (size_t)s * CC + q);
    float* p = agg + (size_t)d * CC + q;
    atomicAdd(p + 0, v.x);
    atomicAdd(p + 1, v.y);
    atomicAdd(p + 2, v.z);
    atomicAdd(p + 3, v.w);
}

// ---------- fused SAGE GEMM: out = [mean|h] @ [Wl;Wr] + b, BN, ReLU, (+x) ----------
// tile: 64 nodes x 128 cols, K=256 in 4 chunks of 64. 256 threads.
// thread (tx=t&15, ty=t>>4): cols j0=tx*8..+7, rows r0=ty*4..+3 -> acc[4][8]
__global__ __launch_bounds__(256) void k_gemm(
    const float* __restrict__ agg, const float* __restrict__ inv,
    const float* __restrict__ hin,
    const float* __restrict__ Wl, const float* __restrict__ Wr,
    const float* __restrict__ bconv,
    const float* __restrict__ bng, const float* __restrict__ bnb,
    const float* __restrict__ bnm, const float* __restrict__ bnv,
    const float* __restrict__ x, int add_res,
    float* __restrict__ hout)
{
    __shared__ float As[64][65];    // [row][k], stride 65 -> bank=(row+k)%32
    __shared__ float Bs[64][132];   // [k][col], padded for staging writes
    const int t = threadIdx.x;
    const int tx = t & 15, ty = t >> 4;
    const int j0 = tx * 8, r0 = ty * 4;
    const int nbase = blockIdx.x * 64;

    float acc[4][8];
#pragma unroll
    for (int i = 0; i < 4; ++i)
#pragma unroll
        for (int j = 0; j < 8; ++j) acc[i][j] = 0.f;

    const int rl = t >> 2;               // staging row 0..63
    const int kq = (t & 3) * 16;         // staging k offset within chunk
    int rowg = nbase + rl;
    if (rowg >= NN) rowg = NN - 1;       // clamp (last block only); safe: same block

#pragma unroll 1
    for (int kc = 0; kc < 4; ++kc) {
        const int kbase = kc * 64;
        // stage A chunk (transformed on the fly: mean = agg*inv for k<128, else h)
        {
            const float* sp;
            float scale;
            if (kc < 2) { sp = agg + (size_t)rowg * CC + (kbase + kq); scale = inv[rowg]; }
            else        { sp = hin + (size_t)rowg * CC + (kbase - 128 + kq); scale = 1.0f; }
#pragma unroll
            for (int i = 0; i < 4; ++i) {
                float4 v = *(const float4*)(sp + i * 4);
                int kk = kq + i * 4;
                As[rl][kk + 0] = v.x * scale;
                As[rl][kk + 1] = v.y * scale;
                As[rl][kk + 2] = v.z * scale;
                As[rl][kk + 3] = v.w * scale;
            }
        }
        // stage B chunk: rows kbase..kbase+63 of [Wl;Wr]
        {
            const float* Wsrc = (kc < 2) ? (Wl + kbase * CC) : (Wr + (kbase - 128) * CC);
#pragma unroll
            for (int i = 0; i < 8; ++i) {
                int fi = (t + i * 256) * 4;      // float index in 64x128 chunk
                int k = fi >> 7, j = fi & 127;
                *(float4*)&Bs[k][j] = *(const float4*)(Wsrc + fi);
            }
        }
        __syncthreads();
#pragma unroll 4
        for (int k = 0; k < 64; ++k) {
            float4 b0 = *(const float4*)&Bs[k][j0];
            float4 b1 = *(const float4*)&Bs[k][j0 + 4];
#pragma unroll
            for (int i = 0; i < 4; ++i) {
                float a = As[r0 + i][k];
                acc[i][0] += a * b0.x; acc[i][1] += a * b0.y;
                acc[i][2] += a * b0.z; acc[i][3] += a * b0.w;
                acc[i][4] += a * b1.x; acc[i][5] += a * b1.y;
                acc[i][6] += a * b1.z; acc[i][7] += a * b1.w;
            }
        }
        __syncthreads();
    }

    // epilogue: +bconv, BN(eval), ReLU, optional residual(+x)
    float s[8], tt[8];
#pragma unroll
    for (int j = 0; j < 8; ++j) {
        int col = j0 + j;
        float sc = bng[col] * rsqrtf(bnv[col] + EPS);
        s[j] = sc;
        tt[j] = (bconv[col] - bnm[col]) * sc + bnb[col];
    }
#pragma unroll
    for (int i = 0; i < 4; ++i) {
        int row = nbase + r0 + i;
        if (row < NN) {
            float o[8];
#pragma unroll
            for (int j = 0; j < 8; ++j) {
                float v = acc[i][j] * s[j] + tt[j];
                o[j] = fmaxf(v, 0.f);
            }
            if (add_res) {
                const float* xp = x + (size_t)row * CC + j0;
#pragma unroll
                for (int j = 0; j < 8; ++j) o[j] += xp[j];
            }
            float* op = hout + (size_t)row * CC + j0;
            *(float4*)op = *(float4*)&o[0];
            *(float4*)(op + 4) = *(float4*)&o[4];
        }
    }
}

// ---------- fused LayerNorm + MLP head: one wave per node ----------
__global__ __launch_bounds__(256) void k_head(
    const float* __restrict__ h,
    const float* __restrict__ lng, const float* __restrict__ lnb,
    const float* __restrict__ W1, const float* __restrict__ b1,
    const float* __restrict__ bog, const float* __restrict__ bob,
    const float* __restrict__ bom, const float* __restrict__ bov,
    const float* __restrict__ W2, const float* __restrict__ b2,
    float* __restrict__ out)
{
    __shared__ float Ws[128][64];   // W1 staged
    __shared__ float hs[4][128];    // per-wave normalized row
    const int t = threadIdx.x;
#pragma unroll
    for (int i = 0; i < 8; ++i) {
        int fi = (t + i * 256) * 4;
        int k = fi >> 6, j = fi & 63;
        *(float4*)&Ws[k][j] = *(const float4*)(W1 + fi);
    }
    __syncthreads();

    const int lane = t & 63, wv = t >> 6;
    const int node = blockIdx.x * 4 + wv;
    const float* hp = h + (size_t)node * CC;
    float v0 = hp[lane], v1 = hp[lane + 64];

    float s1 = v0 + v1, s2 = v0 * v0 + v1 * v1;
#pragma unroll
    for (int o = 32; o >= 1; o >>= 1) {
        s1 += __shfl_xor(s1, o);
        s2 += __shfl_xor(s2, o);
    }
    float mean = s1 * (1.0f / 128.0f);
    float var = s2 * (1.0f / 128.0f) - mean * mean;
    float rstd = rsqrtf(var + EPS);
    float n0 = (v0 - mean) * rstd * lng[lane] + lnb[lane];
    float n1 = (v1 - mean) * rstd * lng[lane + 64] + lnb[lane + 64];
    hs[wv][lane] = n0;
    hs[wv][lane + 64] = n1;

    float acc = b1[lane];
#pragma unroll 8
    for (int k = 0; k < 128; ++k) acc += hs[wv][k] * Ws[k][lane];

    float sc = bog[lane] * rsqrtf(bov[lane] + EPS);
    float tv = (acc - bom[lane]) * sc + bob[lane];
    tv = fmaxf(tv, 0.f);
    float r = tv * W2[lane];
#pragma unroll
    for (int o = 32; o >= 1; o >>= 1) r += __shfl_xor(r, o);
    if (lane == 0) out[node] = r + b2[0];
}

extern "C" void kernel_launch(void* const* d_in, const int* in_sizes, int n_in,
                              void* d_out, int out_size, void* d_ws, size_t ws_size,
                              hipStream_t stream) {
    const float* x     = (const float*)d_in[0];
    const int*   ei    = (const int*)d_in[1];
    const float* Wl    = (const float*)d_in[2];
    const float* Wr    = (const float*)d_in[3];
    const float* bconv = (const float*)d_in[4];
    const float* bng   = (const float*)d_in[5];
    const float* bnb   = (const float*)d_in[6];
    const float* bnm   = (const float*)d_in[7];
    const float* bnv   = (const float*)d_in[8];
    const float* lng   = (const float*)d_in[9];
    const float* lnb   = (const float*)d_in[10];
    const float* W1    = (const float*)d_in[11];
    const float* b1    = (const float*)d_in[12];
    const float* bog   = (const float*)d_in[13];
    const float* bob   = (const float*)d_in[14];
    const float* bom   = (const float*)d_in[15];
    const float* bov   = (const float*)d_in[16];
    const float* W2    = (const float*)d_in[17];
    const float* b2    = (const float*)d_in[18];

    float* agg  = (float*)d_ws;                     // N*C
    float* h    = agg + (size_t)NN * CC;            // N*C
    float* cntf = h + (size_t)NN * CC;              // N
    float* inv  = cntf + NN;                        // N

    // degree (edge-structure only -> once)
    hipMemsetAsync(cntf, 0, NN * sizeof(float), stream);
    k_count<<<(EE + 255) / 256, 256, 0, stream>>>(ei, cntf);
    k_inv<<<(NN + 255) / 256, 256, 0, stream>>>(cntf, inv);

    const float* hin = x;
    for (int l = 0; l < 4; ++l) {
        hipMemsetAsync(agg, 0, (size_t)NN * CC * sizeof(float), stream);
        k_scatter<<<(EE * 32) / 256, 256, 0, stream>>>(ei, hin, agg);
        k_gemm<<<(NN + 63) / 64, 256, 0, stream>>>(
            agg, inv, hin,
            Wl + (size_t)l * CC * CC, Wr + (size_t)l * CC * CC,
            bconv + l * CC, bng + l * CC, bnb + l * CC, bnm + l * CC, bnv + l * CC,
            x, (l == 0) ? 1 : 0, h);
        hin = h;
    }
    k_head<<<NN / 4, 256, 0, stream>>>(h, lng, lnb, W1, b1,
                                       bog, bob, bom, bov, W2, b2, (float*)d_out);
}

// Round 2
// 1255.809 us; speedup vs baseline: 9.0407x; 9.0407x over previous
//
#include <hip/hip_runtime.h>

#define NN 100000
#define EE 1600000
#define CC 128
#define EPS 1e-5f

// ---------- CSR build ----------
__global__ __launch_bounds__(256) void k_count(const int* __restrict__ ei,
                                               int* __restrict__ cnt) {
    int e = blockIdx.x * 256 + threadIdx.x;
    if (e < EE) atomicAdd(&cnt[ei[EE + e]], 1);
}

// single-block exclusive scan over cnt -> row_ptr, plus inv = 1/max(cnt,1)
__global__ __launch_bounds__(1024) void k_scan(const int* __restrict__ cnt,
                                               int* __restrict__ row_ptr,
                                               float* __restrict__ inv) {
    __shared__ int wsum[16];
    __shared__ int cbase;
    const int t = threadIdx.x;
    if (t == 0) cbase = 0;
    __syncthreads();
    for (int base = 0; base < NN; base += 1024) {
        int i = base + t;
        int v = (i < NN) ? cnt[i] : 0;
        int lane = t & 63, w = t >> 6;
        int s = v;
#pragma unroll
        for (int o = 1; o < 64; o <<= 1) {
            int u = __shfl_up(s, o);
            if (lane >= o) s += u;
        }
        if (lane == 63) wsum[w] = s;
        __syncthreads();
        if (t < 16) {
            int ws = wsum[t];
#pragma unroll
            for (int o = 1; o < 16; o <<= 1) {
                int u = __shfl_up(ws, o);
                if (t >= o) ws += u;
            }
            wsum[t] = ws;
        }
        __syncthreads();
        int excl = cbase + (w ? wsum[w - 1] : 0) + (s - v);
        if (i < NN) {
            row_ptr[i] = excl;
            inv[i] = 1.0f / fmaxf((float)v, 1.0f);
        }
        __syncthreads();
        if (t == 0) cbase += wsum[15];
        __syncthreads();
    }
    if (t == 0) row_ptr[NN] = cbase;
}

__global__ __launch_bounds__(256) void k_fill(const int* __restrict__ ei,
                                              const int* __restrict__ row_ptr,
                                              int* __restrict__ fill,
                                              int* __restrict__ col) {
    int e = blockIdx.x * 256 + threadIdx.x;
    if (e < EE) {
        int d = ei[EE + e];
        int pos = row_ptr[d] + atomicAdd(&fill[d], 1);
        col[pos] = ei[e];
    }
}

// ---------- gather-mean: one wave per node, 2-way edge ILP ----------
__global__ __launch_bounds__(256) void k_gather(const int* __restrict__ row_ptr,
                                                const int* __restrict__ col,
                                                const float* __restrict__ hsrc,
                                                const float* __restrict__ inv,
                                                float* __restrict__ agg) {
    int node = blockIdx.x * 4 + (threadIdx.x >> 6);
    if (node >= NN) return;
    int lane = threadIdx.x & 63;
    int c4 = (lane & 31) << 2;       // channel offset, 32 lanes cover 128
    int par = lane >> 5;             // 0/1 edge parity
    int beg = row_ptr[node], end = row_ptr[node + 1];
    float4 acc = make_float4(0.f, 0.f, 0.f, 0.f);
    for (int j = beg + par; j < end; j += 2) {
        int s = col[j];
        float4 v = *(const float4*)(hsrc + (size_t)s * CC + c4);
        acc.x += v.x; acc.y += v.y; acc.z += v.z; acc.w += v.w;
    }
    acc.x += __shfl_xor(acc.x, 32);
    acc.y += __shfl_xor(acc.y, 32);
    acc.z += __shfl_xor(acc.z, 32);
    acc.w += __shfl_xor(acc.w, 32);
    if (par == 0) {
        float sc = inv[node];
        acc.x *= sc; acc.y *= sc; acc.z *= sc; acc.w *= sc;
        *(float4*)(agg + (size_t)node * CC + c4) = acc;
    }
}

// ---------- fused SAGE GEMM: out = [mean|h] @ [Wl;Wr] + b, BN, ReLU, (+x) ----------
__global__ __launch_bounds__(256) void k_gemm(
    const float* __restrict__ agg, const float* __restrict__ hin,
    const float* __restrict__ Wl, const float* __restrict__ Wr,
    const float* __restrict__ bconv,
    const float* __restrict__ bng, const float* __restrict__ bnb,
    const float* __restrict__ bnm, const float* __restrict__ bnv,
    const float* __restrict__ x, int add_res,
    float* __restrict__ hout)
{
    __shared__ float As[64][65];
    __shared__ float Bs[64][132];
    const int t = threadIdx.x;
    const int tx = t & 15, ty = t >> 4;
    const int j0 = tx * 8, r0 = ty * 4;
    const int nbase = blockIdx.x * 64;

    float acc[4][8];
#pragma unroll
    for (int i = 0; i < 4; ++i)
#pragma unroll
        for (int j = 0; j < 8; ++j) acc[i][j] = 0.f;

    const int rl = t >> 2;
    const int kq = (t & 3) * 16;
    int rowg = nbase + rl;
    if (rowg >= NN) rowg = NN - 1;

#pragma unroll 1
    for (int kc = 0; kc < 4; ++kc) {
        const int kbase = kc * 64;
        {
            const float* sp = (kc < 2) ? agg + (size_t)rowg * CC + (kbase + kq)
                                       : hin + (size_t)rowg * CC + (kbase - 128 + kq);
#pragma unroll
            for (int i = 0; i < 4; ++i) {
                float4 v = *(const float4*)(sp + i * 4);
                int kk = kq + i * 4;
                As[rl][kk + 0] = v.x;
                As[rl][kk + 1] = v.y;
                As[rl][kk + 2] = v.z;
                As[rl][kk + 3] = v.w;
            }
        }
        {
            const float* Wsrc = (kc < 2) ? (Wl + kbase * CC) : (Wr + (kbase - 128) * CC);
#pragma unroll
            for (int i = 0; i < 8; ++i) {
                int fi = (t + i * 256) * 4;
                int k = fi >> 7, j = fi & 127;
                *(float4*)&Bs[k][j] = *(const float4*)(Wsrc + fi);
            }
        }
        __syncthreads();
#pragma unroll 4
        for (int k = 0; k < 64; ++k) {
            float4 b0 = *(const float4*)&Bs[k][j0];
            float4 b1 = *(const float4*)&Bs[k][j0 + 4];
#pragma unroll
            for (int i = 0; i < 4; ++i) {
                float a = As[r0 + i][k];
                acc[i][0] += a * b0.x; acc[i][1] += a * b0.y;
                acc[i][2] += a * b0.z; acc[i][3] += a * b0.w;
                acc[i][4] += a * b1.x; acc[i][5] += a * b1.y;
                acc[i][6] += a * b1.z; acc[i][7] += a * b1.w;
            }
        }
        __syncthreads();
    }

    float s[8], tt[8];
#pragma unroll
    for (int j = 0; j < 8; ++j) {
        int col = j0 + j;
        float sc = bng[col] * rsqrtf(bnv[col] + EPS);
        s[j] = sc;
        tt[j] = (bconv[col] - bnm[col]) * sc + bnb[col];
    }
#pragma unroll
    for (int i = 0; i < 4; ++i) {
        int row = nbase + r0 + i;
        if (row < NN) {
            float o[8];
#pragma unroll
            for (int j = 0; j < 8; ++j) {
                float v = acc[i][j] * s[j] + tt[j];
                o[j] = fmaxf(v, 0.f);
            }
            if (add_res) {
                const float* xp = x + (size_t)row * CC + j0;
#pragma unroll
                for (int j = 0; j < 8; ++j) o[j] += xp[j];
            }
            float* op = hout + (size_t)row * CC + j0;
            *(float4*)op = *(float4*)&o[0];
            *(float4*)(op + 4) = *(float4*)&o[4];
        }
    }
}

// ---------- fused LayerNorm + MLP head ----------
__global__ __launch_bounds__(256) void k_head(
    const float* __restrict__ h,
    const float* __restrict__ lng, const float* __restrict__ lnb,
    const float* __restrict__ W1, const float* __restrict__ b1,
    const float* __restrict__ bog, const float* __restrict__ bob,
    const float* __restrict__ bom, const float* __restrict__ bov,
    const float* __restrict__ W2, const float* __restrict__ b2,
    float* __restrict__ out)
{
    __shared__ float Ws[128][64];
    __shared__ float hs[4][128];
    const int t = threadIdx.x;
#pragma unroll
    for (int i = 0; i < 8; ++i) {
        int fi = (t + i * 256) * 4;
        int k = fi >> 6, j = fi & 63;
        *(float4*)&Ws[k][j] = *(const float4*)(W1 + fi);
    }
    __syncthreads();

    const int lane = t & 63, wv = t >> 6;
    const int node = blockIdx.x * 4 + wv;
    const float* hp = h + (size_t)node * CC;
    float v0 = hp[lane], v1 = hp[lane + 64];

    float s1 = v0 + v1, s2 = v0 * v0 + v1 * v1;
#pragma unroll
    for (int o = 32; o >= 1; o >>= 1) {
        s1 += __shfl_xor(s1, o);
        s2 += __shfl_xor(s2, o);
    }
    float mean = s1 * (1.0f / 128.0f);
    float var = s2 * (1.0f / 128.0f) - mean * mean;
    float rstd = rsqrtf(var + EPS);
    float n0 = (v0 - mean) * rstd * lng[lane] + lnb[lane];
    float n1 = (v1 - mean) * rstd * lng[lane + 64] + lnb[lane + 64];
    hs[wv][lane] = n0;
    hs[wv][lane + 64] = n1;

    float acc = b1[lane];
#pragma unroll 8
    for (int k = 0; k < 128; ++k) acc += hs[wv][k] * Ws[k][lane];

    float sc = bog[lane] * rsqrtf(bov[lane] + EPS);
    float tv = (acc - bom[lane]) * sc + bob[lane];
    tv = fmaxf(tv, 0.f);
    float r = tv * W2[lane];
#pragma unroll
    for (int o = 32; o >= 1; o >>= 1) r += __shfl_xor(r, o);
    if (lane == 0) out[node] = r + b2[0];
}

extern "C" void kernel_launch(void* const* d_in, const int* in_sizes, int n_in,
                              void* d_out, int out_size, void* d_ws, size_t ws_size,
                              hipStream_t stream) {
    const float* x     = (const float*)d_in[0];
    const int*   ei    = (const int*)d_in[1];
    const float* Wl    = (const float*)d_in[2];
    const float* Wr    = (const float*)d_in[3];
    const float* bconv = (const float*)d_in[4];
    const float* bng   = (const float*)d_in[5];
    const float* bnb   = (const float*)d_in[6];
    const float* bnm   = (const float*)d_in[7];
    const float* bnv   = (const float*)d_in[8];
    const float* lng   = (const float*)d_in[9];
    const float* lnb   = (const float*)d_in[10];
    const float* W1    = (const float*)d_in[11];
    const float* b1    = (const float*)d_in[12];
    const float* bog   = (const float*)d_in[13];
    const float* bob   = (const float*)d_in[14];
    const float* bom   = (const float*)d_in[15];
    const float* bov   = (const float*)d_in[16];
    const float* W2    = (const float*)d_in[17];
    const float* b2    = (const float*)d_in[18];

    float* agg   = (float*)d_ws;                       // N*C
    float* h     = agg + (size_t)NN * CC;              // N*C
    float* inv   = h + (size_t)NN * CC;                // N
    int*   cnt   = (int*)(inv + NN);                   // N
    int*   row_ptr = cnt + NN;                         // N+1
    int*   fill  = row_ptr + NN + 1;                   // N
    int*   col   = fill + NN;                          // E

    hipMemsetAsync(cnt, 0, NN * sizeof(int), stream);
    hipMemsetAsync(fill, 0, NN * sizeof(int), stream);
    k_count<<<(EE + 255) / 256, 256, 0, stream>>>(ei, cnt);
    k_scan<<<1, 1024, 0, stream>>>(cnt, row_ptr, inv);
    k_fill<<<(EE + 255) / 256, 256, 0, stream>>>(ei, row_ptr, fill, col);

    const float* hin = x;
    for (int l = 0; l < 4; ++l) {
        k_gather<<<(NN + 3) / 4, 256, 0, stream>>>(row_ptr, col, hin, inv, agg);
        k_gemm<<<(NN + 63) / 64, 256, 0, stream>>>(
            agg, hin,
            Wl + (size_t)l * CC * CC, Wr + (size_t)l * CC * CC,
            bconv + l * CC, bng + l * CC, bnb + l * CC, bnm + l * CC, bnv + l * CC,
            x, (l == 0) ? 1 : 0, h);
        hin = h;
    }
    k_head<<<NN / 4, 256, 0, stream>>>(h, lng, lnb, W1, b1,
                                       bog, bob, bom, bov, W2, b2, (float*)d_out);
}

// Round 3
// 803.178 us; speedup vs baseline: 14.1356x; 1.5635x over previous
//
#include <hip/hip_runtime.h>

#define NN 100000
#define EE 1600000
#define CC 128
#define EPS 1e-5f

typedef __attribute__((ext_vector_type(8))) short sh8;
typedef __attribute__((ext_vector_type(4))) float fl4;

static __device__ __forceinline__ unsigned short f2bf(float f) {
    unsigned u = __float_as_uint(f);
    u = (u + 0x7fff + ((u >> 16) & 1)) >> 16;   // round-to-nearest-even
    return (unsigned short)u;
}
static __device__ __forceinline__ float bf2f(unsigned short s) {
    return __uint_as_float((unsigned)s << 16);
}

// ---------- CSR build ----------
__global__ __launch_bounds__(256) void k_count(const int* __restrict__ ei,
                                               int* __restrict__ cnt) {
    int e = blockIdx.x * 256 + threadIdx.x;
    if (e < EE) atomicAdd(&cnt[ei[EE + e]], 1);
}

__global__ __launch_bounds__(1024) void k_scan(const int* __restrict__ cnt,
                                               int* __restrict__ row_ptr,
                                               float* __restrict__ inv) {
    __shared__ int wsum[16];
    __shared__ int cbase;
    const int t = threadIdx.x;
    if (t == 0) cbase = 0;
    __syncthreads();
    for (int base = 0; base < NN; base += 1024) {
        int i = base + t;
        int v = (i < NN) ? cnt[i] : 0;
        int lane = t & 63, w = t >> 6;
        int s = v;
#pragma unroll
        for (int o = 1; o < 64; o <<= 1) {
            int u = __shfl_up(s, o);
            if (lane >= o) s += u;
        }
        if (lane == 63) wsum[w] = s;
        __syncthreads();
        if (t < 16) {
            int ws = wsum[t];
#pragma unroll
            for (int o = 1; o < 16; o <<= 1) {
                int u = __shfl_up(ws, o);
                if (t >= o) ws += u;
            }
            wsum[t] = ws;
        }
        __syncthreads();
        int excl = cbase + (w ? wsum[w - 1] : 0) + (s - v);
        if (i < NN) {
            row_ptr[i] = excl;
            inv[i] = 1.0f / fmaxf((float)v, 1.0f);
        }
        __syncthreads();
        if (t == 0) cbase += wsum[15];
        __syncthreads();
    }
    if (t == 0) row_ptr[NN] = cbase;
}

__global__ __launch_bounds__(256) void k_fill(const int* __restrict__ ei,
                                              const int* __restrict__ row_ptr,
                                              int* __restrict__ fill,
                                              int* __restrict__ col) {
    int e = blockIdx.x * 256 + threadIdx.x;
    if (e < EE) {
        int d = ei[EE + e];
        int pos = row_ptr[d] + atomicAdd(&fill[d], 1);
        col[pos] = ei[e];
    }
}

// ---------- x fp32 -> A2 h-columns bf16 ----------
__global__ __launch_bounds__(256) void k_cvtx(const float* __restrict__ x,
                                              unsigned short* __restrict__ A2) {
    int id = blockIdx.x * 256 + threadIdx.x;   // N*CC/8 threads
    if (id >= NN * CC / 8) return;
    int row = id >> 4, g = id & 15;
    const float* xp = x + (size_t)row * CC + g * 8;
    unsigned short o[8];
#pragma unroll
    for (int e = 0; e < 8; ++e) o[e] = f2bf(xp[e]);
    *(sh8*)(A2 + (size_t)row * 256 + 128 + g * 8) = *(sh8*)o;
}

// ---------- build Wfrag: per-layer [ks][nt][lane][8] bf16 fragment order ----------
__global__ __launch_bounds__(256) void k_wcvt(const float* __restrict__ Wl,
                                              const float* __restrict__ Wr,
                                              unsigned short* __restrict__ Wfrag) {
    int id = blockIdx.x * 256 + threadIdx.x;   // 4*8*8*64 = 16384
    if (id >= 16384) return;
    int lay = id >> 12;
    int rem = id & 4095;
    int ks = rem >> 9;
    int nt = (rem >> 6) & 7;
    int l = rem & 63;
    int c = nt * 16 + (l & 15);
    int kb = ks * 32 + (l >> 4) * 8;
    const float* WL = Wl + (size_t)lay * CC * CC;
    const float* WR = Wr + (size_t)lay * CC * CC;
    unsigned short o[8];
#pragma unroll
    for (int e = 0; e < 8; ++e) {
        int k = kb + e;
        float v = (k < 128) ? WL[(size_t)k * CC + c] : WR[(size_t)(k - 128) * CC + c];
        o[e] = f2bf(v);
    }
    *(sh8*)(Wfrag + (size_t)lay * 32768 + ks * 4096 + nt * 512 + l * 8) = *(sh8*)o;
}

// ---------- gather-mean (bf16 in, bf16 out): 16 lanes/channel-strip, 4-way edge ILP ----------
__global__ __launch_bounds__(256) void k_gather(const int* __restrict__ row_ptr,
                                                const int* __restrict__ col,
                                                unsigned short* __restrict__ A2,
                                                const float* __restrict__ inv) {
    int node = blockIdx.x * 4 + (threadIdx.x >> 6);
    if (node >= NN) return;
    int lane = threadIdx.x & 63;
    int g = lane & 15;          // channel strip: 8 bf16
    int par = lane >> 4;        // edge parity 0..3
    const unsigned short* hbase = A2 + 128 + g * 8;
    int beg = row_ptr[node], end = row_ptr[node + 1];
    float acc[8];
#pragma unroll
    for (int e = 0; e < 8; ++e) acc[e] = 0.f;
    for (int j = beg + par; j < end; j += 4) {
        int s = col[j];
        sh8 v = *(const sh8*)(hbase + (size_t)s * 256);
#pragma unroll
        for (int e = 0; e < 8; ++e) acc[e] += bf2f((unsigned short)v[e]);
    }
#pragma unroll
    for (int e = 0; e < 8; ++e) {
        acc[e] += __shfl_xor(acc[e], 16);
        acc[e] += __shfl_xor(acc[e], 32);
    }
    if (par == 0) {
        float sc = inv[node];
        unsigned short o[8];
#pragma unroll
        for (int e = 0; e < 8; ++e) o[e] = f2bf(acc[e] * sc);
        *(sh8*)(A2 + (size_t)node * 256 + g * 8) = *(sh8*)o;
    }
}

// ---------- MFMA GEMM: A2[row] (256 bf16) @ Wfrag -> BN+ReLU(+x) -> A2 h-cols ----------
// 256 thr = 4 waves; wave w: rows blockIdx*64 + w*16 .. +15, all 128 cols.
__global__ __launch_bounds__(256) void k_gemm(
    const unsigned short* __restrict__ A2w,   // read base (same buffer)
    unsigned short* __restrict__ A2,          // write base
    const unsigned short* __restrict__ Wfrag, // per-layer, fragment order
    const float* __restrict__ bconv,
    const float* __restrict__ bng, const float* __restrict__ bnb,
    const float* __restrict__ bnm, const float* __restrict__ bnv,
    const float* __restrict__ x, int add_res)
{
    const int t = threadIdx.x;
    const int w = t >> 6, l = t & 63;
    const int rowbase = blockIdx.x * 64 + w * 16;
    int r_a = rowbase + (l & 15);
    if (r_a >= NN) r_a = NN - 1;
    const unsigned short* arow = A2w + (size_t)r_a * 256 + (l >> 4) * 8;

    fl4 acc[8];
#pragma unroll
    for (int nt = 0; nt < 8; ++nt) acc[nt] = (fl4){0.f, 0.f, 0.f, 0.f};

#pragma unroll
    for (int ks = 0; ks < 8; ++ks) {
        sh8 a = *(const sh8*)(arow + ks * 32);
        const unsigned short* wk = Wfrag + ks * 4096 + l * 8;
#pragma unroll
        for (int nt = 0; nt < 8; ++nt) {
            sh8 b = *(const sh8*)(wk + nt * 512);
            acc[nt] = __builtin_amdgcn_mfma_f32_16x16x32_bf16(a, b, acc[nt], 0, 0, 0);
        }
    }

    const int r0 = rowbase + (l >> 4) * 4;
#pragma unroll
    for (int nt = 0; nt < 8; ++nt) {
        int c = nt * 16 + (l & 15);
        float sc = bng[c] * rsqrtf(bnv[c] + EPS);
        float tt = (bconv[c] - bnm[c]) * sc + bnb[c];
#pragma unroll
        for (int j = 0; j < 4; ++j) {
            int row = r0 + j;
            if (row < NN) {
                float v = acc[nt][j] * sc + tt;
                v = fmaxf(v, 0.f);
                if (add_res) v += x[(size_t)row * CC + c];
                A2[(size_t)row * 256 + 128 + c] = f2bf(v);
            }
        }
    }
}

// ---------- fused LayerNorm + MLP head (reads bf16 h) ----------
__global__ __launch_bounds__(256) void k_head(
    const unsigned short* __restrict__ A2,
    const float* __restrict__ lng, const float* __restrict__ lnb,
    const float* __restrict__ W1, const float* __restrict__ b1,
    const float* __restrict__ bog, const float* __restrict__ bob,
    const float* __restrict__ bom, const float* __restrict__ bov,
    const float* __restrict__ W2, const float* __restrict__ b2,
    float* __restrict__ out)
{
    __shared__ float Ws[128][64];
    __shared__ float hs[4][128];
    const int t = threadIdx.x;
#pragma unroll
    for (int i = 0; i < 8; ++i) {
        int fi = (t + i * 256) * 4;
        int k = fi >> 6, j = fi & 63;
        *(float4*)&Ws[k][j] = *(const float4*)(W1 + fi);
    }
    __syncthreads();

    const int lane = t & 63, wv = t >> 6;
    const int node = blockIdx.x * 4 + wv;
    const unsigned short* hp = A2 + (size_t)node * 256 + 128;
    float v0 = bf2f(hp[lane]), v1 = bf2f(hp[lane + 64]);

    float s1 = v0 + v1, s2 = v0 * v0 + v1 * v1;
#pragma unroll
    for (int o = 32; o >= 1; o >>= 1) {
        s1 += __shfl_xor(s1, o);
        s2 += __shfl_xor(s2, o);
    }
    float mean = s1 * (1.0f / 128.0f);
    float var = s2 * (1.0f / 128.0f) - mean * mean;
    float rstd = rsqrtf(var + EPS);
    float n0 = (v0 - mean) * rstd * lng[lane] + lnb[lane];
    float n1 = (v1 - mean) * rstd * lng[lane + 64] + lnb[lane + 64];
    hs[wv][lane] = n0;
    hs[wv][lane + 64] = n1;

    float acc = b1[lane];
#pragma unroll 8
    for (int k = 0; k < 128; ++k) acc += hs[wv][k] * Ws[k][lane];

    float sc = bog[lane] * rsqrtf(bov[lane] + EPS);
    float tv = (acc - bom[lane]) * sc + bob[lane];
    tv = fmaxf(tv, 0.f);
    float r = tv * W2[lane];
#pragma unroll
    for (int o = 32; o >= 1; o >>= 1) r += __shfl_xor(r, o);
    if (lane == 0) out[node] = r + b2[0];
}

extern "C" void kernel_launch(void* const* d_in, const int* in_sizes, int n_in,
                              void* d_out, int out_size, void* d_ws, size_t ws_size,
                              hipStream_t stream) {
    const float* x     = (const float*)d_in[0];
    const int*   ei    = (const int*)d_in[1];
    const float* Wl    = (const float*)d_in[2];
    const float* Wr    = (const float*)d_in[3];
    const float* bconv = (const float*)d_in[4];
    const float* bng   = (const float*)d_in[5];
    const float* bnb   = (const float*)d_in[6];
    const float* bnm   = (const float*)d_in[7];
    const float* bnv   = (const float*)d_in[8];
    const float* lng   = (const float*)d_in[9];
    const float* lnb   = (const float*)d_in[10];
    const float* W1    = (const float*)d_in[11];
    const float* b1    = (const float*)d_in[12];
    const float* bog   = (const float*)d_in[13];
    const float* bob   = (const float*)d_in[14];
    const float* bom   = (const float*)d_in[15];
    const float* bov   = (const float*)d_in[16];
    const float* W2    = (const float*)d_in[17];
    const float* b2    = (const float*)d_in[18];

    unsigned short* A2    = (unsigned short*)d_ws;            // N*256 bf16
    unsigned short* Wfrag = A2 + (size_t)NN * 256;            // 4*32768 bf16
    float* inv    = (float*)(Wfrag + 4 * 32768);              // N
    int*   cnt    = (int*)(inv + NN);                         // N
    int*   row_ptr = cnt + NN;                                // N+1
    int*   fill   = row_ptr + NN + 1;                         // N
    int*   col    = fill + NN;                                // E

    hipMemsetAsync(cnt, 0, NN * sizeof(int), stream);
    hipMemsetAsync(fill, 0, NN * sizeof(int), stream);
    k_cvtx<<<(NN * CC / 8 + 255) / 256, 256, 0, stream>>>(x, A2);
    k_wcvt<<<64, 256, 0, stream>>>(Wl, Wr, Wfrag);
    k_count<<<(EE + 255) / 256, 256, 0, stream>>>(ei, cnt);
    k_scan<<<1, 1024, 0, stream>>>(cnt, row_ptr, inv);
    k_fill<<<(EE + 255) / 256, 256, 0, stream>>>(ei, row_ptr, fill, col);

    for (int l = 0; l < 4; ++l) {
        k_gather<<<(NN + 3) / 4, 256, 0, stream>>>(row_ptr, col, A2, inv);
        k_gemm<<<(NN + 63) / 64, 256, 0, stream>>>(
            A2, A2, Wfrag + (size_t)l * 32768,
            bconv + l * CC, bng + l * CC, bnb + l * CC, bnm + l * CC, bnv + l * CC,
            x, (l == 0) ? 1 : 0);
    }
    k_head<<<NN / 4, 256, 0, stream>>>(A2, lng, lnb, W1, b1,
                                       bog, bob, bom, bov, W2, b2, (float*)d_out);
}

// Round 7
// 801.592 us; speedup vs baseline: 14.1636x; 1.0020x over previous
//
#include <hip/hip_runtime.h>

#define NN 100000
#define EE 1600000
#define CC 128
#define EPS 1e-5f

typedef __attribute__((ext_vector_type(8))) short sh8;
typedef __attribute__((ext_vector_type(4))) float fl4;

static __device__ __forceinline__ unsigned short f2bf(float f) {
    unsigned u = __float_as_uint(f);
    u = (u + 0x7fff + ((u >> 16) & 1)) >> 16;   // round-to-nearest-even
    return (unsigned short)u;
}
static __device__ __forceinline__ float bf2f(unsigned short s) {
    return __uint_as_float((unsigned)s << 16);
}

// ---------- CSR build ----------
__global__ __launch_bounds__(256) void k_count(const int* __restrict__ ei,
                                               int* __restrict__ cnt) {
    int e = blockIdx.x * 256 + threadIdx.x;
    if (e < EE) atomicAdd(&cnt[ei[EE + e]], 1);
}

// single-block exclusive scan over cnt -> row_ptr, plus inv = 1/max(cnt,1)
// (round-3 validated version, 1 element/thread)
__global__ __launch_bounds__(1024) void k_scan(const int* __restrict__ cnt,
                                               int* __restrict__ row_ptr,
                                               float* __restrict__ inv) {
    __shared__ int wsum[16];
    __shared__ int cbase;
    const int t = threadIdx.x;
    if (t == 0) cbase = 0;
    __syncthreads();
    for (int base = 0; base < NN; base += 1024) {
        int i = base + t;
        int v = (i < NN) ? cnt[i] : 0;
        int lane = t & 63, w = t >> 6;
        int s = v;
#pragma unroll
        for (int o = 1; o < 64; o <<= 1) {
            int u = __shfl_up(s, o);
            if (lane >= o) s += u;
        }
        if (lane == 63) wsum[w] = s;
        __syncthreads();
        if (t < 16) {
            int ws = wsum[t];
#pragma unroll
            for (int o = 1; o < 16; o <<= 1) {
                int u = __shfl_up(ws, o);
                if (t >= o) ws += u;
            }
            wsum[t] = ws;
        }
        __syncthreads();
        int excl = cbase + (w ? wsum[w - 1] : 0) + (s - v);
        if (i < NN) {
            row_ptr[i] = excl;
            inv[i] = 1.0f / fmaxf((float)v, 1.0f);
        }
        __syncthreads();
        if (t == 0) cbase += wsum[15];
        __syncthreads();
    }
    if (t == 0) row_ptr[NN] = cbase;
}

__global__ __launch_bounds__(256) void k_fill(const int* __restrict__ ei,
                                              const int* __restrict__ row_ptr,
                                              int* __restrict__ fill,
                                              int* __restrict__ col) {
    int e = blockIdx.x * 256 + threadIdx.x;
    if (e < EE) {
        int d = ei[EE + e];
        int pos = row_ptr[d] + atomicAdd(&fill[d], 1);
        col[pos] = ei[e];
    }
}

// ---------- x fp32 -> A2 h-columns bf16 ----------
__global__ __launch_bounds__(256) void k_cvtx(const float* __restrict__ x,
                                              unsigned short* __restrict__ A2) {
    int id = blockIdx.x * 256 + threadIdx.x;
    if (id >= NN * CC / 8) return;
    int row = id >> 4, g = id & 15;
    const float* xp = x + (size_t)row * CC + g * 8;
    unsigned short o[8];
#pragma unroll
    for (int e = 0; e < 8; ++e) o[e] = f2bf(xp[e]);
    *(sh8*)(A2 + (size_t)row * 256 + 128 + g * 8) = *(sh8*)o;
}

// ---------- build Wfrag (layers): [lay][ks][nt][lane][8] ----------
__global__ __launch_bounds__(256) void k_wcvt(const float* __restrict__ Wl,
                                              const float* __restrict__ Wr,
                                              unsigned short* __restrict__ Wfrag) {
    int id = blockIdx.x * 256 + threadIdx.x;   // 16384
    if (id >= 16384) return;
    int lay = id >> 12;
    int rem = id & 4095;
    int ks = rem >> 9;
    int nt = (rem >> 6) & 7;
    int l = rem & 63;
    int c = nt * 16 + (l & 15);
    int kb = ks * 32 + (l >> 4) * 8;
    const float* WL = Wl + (size_t)lay * CC * CC;
    const float* WR = Wr + (size_t)lay * CC * CC;
    unsigned short o[8];
#pragma unroll
    for (int e = 0; e < 8; ++e) {
        int k = kb + e;
        float v = (k < 128) ? WL[(size_t)k * CC + c] : WR[(size_t)(k - 128) * CC + c];
        o[e] = f2bf(v);
    }
    *(sh8*)(Wfrag + (size_t)lay * 32768 + ks * 4096 + nt * 512 + l * 8) = *(sh8*)o;
}

// ---------- gather-mean (bf16): wave per node, 4-way edge ILP ----------
__global__ __launch_bounds__(256) void k_gather(const int* __restrict__ row_ptr,
                                                const int* __restrict__ col,
                                                unsigned short* __restrict__ A2,
                                                const float* __restrict__ inv) {
    int node = blockIdx.x * 4 + (threadIdx.x >> 6);
    if (node >= NN) return;
    int lane = threadIdx.x & 63;
    int g = lane & 15;
    int par = lane >> 4;
    const unsigned short* hbase = A2 + 128 + g * 8;
    int beg = row_ptr[node], end = row_ptr[node + 1];
    float acc[8];
#pragma unroll
    for (int e = 0; e < 8; ++e) acc[e] = 0.f;
    for (int j = beg + par; j < end; j += 4) {
        int s = col[j];
        sh8 v = *(const sh8*)(hbase + (size_t)s * 256);
#pragma unroll
        for (int e = 0; e < 8; ++e) acc[e] += bf2f((unsigned short)v[e]);
    }
#pragma unroll
    for (int e = 0; e < 8; ++e) {
        acc[e] += __shfl_xor(acc[e], 16);
        acc[e] += __shfl_xor(acc[e], 32);
    }
    if (par == 0) {
        float sc = inv[node];
        unsigned short o[8];
#pragma unroll
        for (int e = 0; e < 8; ++e) o[e] = f2bf(acc[e] * sc);
        *(sh8*)(A2 + (size_t)node * 256 + g * 8) = *(sh8*)o;
    }
}

// ---------- MFMA GEMM: A2 @ Wfrag -> BN+ReLU(+x) -> A2 h-cols ----------
__global__ __launch_bounds__(256) void k_gemm(
    const unsigned short* __restrict__ A2w,
    unsigned short* __restrict__ A2,
    const unsigned short* __restrict__ Wfrag,
    const float* __restrict__ bconv,
    const float* __restrict__ bng, const float* __restrict__ bnb,
    const float* __restrict__ bnm, const float* __restrict__ bnv,
    const float* __restrict__ x, int add_res)
{
    const int t = threadIdx.x;
    const int w = t >> 6, l = t & 63;
    const int rowbase = blockIdx.x * 64 + w * 16;
    int r_a = rowbase + (l & 15);
    if (r_a >= NN) r_a = NN - 1;
    const unsigned short* arow = A2w + (size_t)r_a * 256 + (l >> 4) * 8;

    fl4 acc[8];
#pragma unroll
    for (int nt = 0; nt < 8; ++nt) acc[nt] = (fl4){0.f, 0.f, 0.f, 0.f};

#pragma unroll
    for (int ks = 0; ks < 8; ++ks) {
        sh8 a = *(const sh8*)(arow + ks * 32);
        const unsigned short* wk = Wfrag + ks * 4096 + l * 8;
#pragma unroll
        for (int nt = 0; nt < 8; ++nt) {
            sh8 b = *(const sh8*)(wk + nt * 512);
            acc[nt] = __builtin_amdgcn_mfma_f32_16x16x32_bf16(a, b, acc[nt], 0, 0, 0);
        }
    }

    const int r0 = rowbase + (l >> 4) * 4;
#pragma unroll
    for (int nt = 0; nt < 8; ++nt) {
        int c = nt * 16 + (l & 15);
        float sc = bng[c] * rsqrtf(bnv[c] + EPS);
        float tt = (bconv[c] - bnm[c]) * sc + bnb[c];
#pragma unroll
        for (int j = 0; j < 4; ++j) {
            int row = r0 + j;
            if (row < NN) {
                float v = acc[nt][j] * sc + tt;
                v = fmaxf(v, 0.f);
                if (add_res) v += x[(size_t)row * CC + c];
                A2[(size_t)row * 256 + 128 + c] = f2bf(v);
            }
        }
    }
}

// ---------- fused LayerNorm + MLP head (round-3 validated LDS version) ----------
__global__ __launch_bounds__(256) void k_head(
    const unsigned short* __restrict__ A2,
    const float* __restrict__ lng, const float* __restrict__ lnb,
    const float* __restrict__ W1, const float* __restrict__ b1,
    const float* __restrict__ bog, const float* __restrict__ bob,
    const float* __restrict__ bom, const float* __restrict__ bov,
    const float* __restrict__ W2, const float* __restrict__ b2,
    float* __restrict__ out)
{
    __shared__ float Ws[128][64];
    __shared__ float hs[4][128];
    const int t = threadIdx.x;
#pragma unroll
    for (int i = 0; i < 8; ++i) {
        int fi = (t + i * 256) * 4;
        int k = fi >> 6, j = fi & 63;
        *(float4*)&Ws[k][j] = *(const float4*)(W1 + fi);
    }
    __syncthreads();

    const int lane = t & 63, wv = t >> 6;
    const int node = blockIdx.x * 4 + wv;
    const unsigned short* hp = A2 + (size_t)node * 256 + 128;
    float v0 = bf2f(hp[lane]), v1 = bf2f(hp[lane + 64]);

    float s1 = v0 + v1, s2 = v0 * v0 + v1 * v1;
#pragma unroll
    for (int o = 32; o >= 1; o >>= 1) {
        s1 += __shfl_xor(s1, o);
        s2 += __shfl_xor(s2, o);
    }
    float mean = s1 * (1.0f / 128.0f);
    float var = s2 * (1.0f / 128.0f) - mean * mean;
    float rstd = rsqrtf(var + EPS);
    float n0 = (v0 - mean) * rstd * lng[lane] + lnb[lane];
    float n1 = (v1 - mean) * rstd * lng[lane + 64] + lnb[lane + 64];
    hs[wv][lane] = n0;
    hs[wv][lane + 64] = n1;

    float acc = b1[lane];
#pragma unroll 8
    for (int k = 0; k < 128; ++k) acc += hs[wv][k] * Ws[k][lane];

    float sc = bog[lane] * rsqrtf(bov[lane] + EPS);
    float tv = (acc - bom[lane]) * sc + bob[lane];
    tv = fmaxf(tv, 0.f);
    float r = tv * W2[lane];
#pragma unroll
    for (int o = 32; o >= 1; o >>= 1) r += __shfl_xor(r, o);
    if (lane == 0) out[node] = r + b2[0];
}

extern "C" void kernel_launch(void* const* d_in, const int* in_sizes, int n_in,
                              void* d_out, int out_size, void* d_ws, size_t ws_size,
                              hipStream_t stream) {
    const float* x     = (const float*)d_in[0];
    const int*   ei    = (const int*)d_in[1];
    const float* Wl    = (const float*)d_in[2];
    const float* Wr    = (const float*)d_in[3];
    const float* bconv = (const float*)d_in[4];
    const float* bng   = (const float*)d_in[5];
    const float* bnb   = (const float*)d_in[6];
    const float* bnm   = (const float*)d_in[7];
    const float* bnv   = (const float*)d_in[8];
    const float* lng   = (const float*)d_in[9];
    const float* lnb   = (const float*)d_in[10];
    const float* W1    = (const float*)d_in[11];
    const float* b1    = (const float*)d_in[12];
    const float* bog   = (const float*)d_in[13];
    const float* bob   = (const float*)d_in[14];
    const float* bom   = (const float*)d_in[15];
    const float* bov   = (const float*)d_in[16];
    const float* W2    = (const float*)d_in[17];
    const float* b2    = (const float*)d_in[18];

    unsigned short* A2     = (unsigned short*)d_ws;           // N*256
    unsigned short* Wfrag  = A2 + (size_t)NN * 256;           // 4*32768
    float* inv     = (float*)(Wfrag + 4 * 32768);             // N
    int*   cnt     = (int*)(inv + NN);                        // N
    int*   fill    = cnt + NN;                                // N (adjacent -> one memset)
    int*   row_ptr = fill + NN;                               // N+1
    int*   col     = row_ptr + NN + 1;                        // E

    hipMemsetAsync(cnt, 0, 2 * NN * sizeof(int), stream);
    k_cvtx<<<(NN * CC / 8 + 255) / 256, 256, 0, stream>>>(x, A2);
    k_wcvt<<<64, 256, 0, stream>>>(Wl, Wr, Wfrag);
    k_count<<<(EE + 255) / 256, 256, 0, stream>>>(ei, cnt);
    k_scan<<<1, 1024, 0, stream>>>(cnt, row_ptr, inv);
    k_fill<<<(EE + 255) / 256, 256, 0, stream>>>(ei, row_ptr, fill, col);

    for (int l = 0; l < 4; ++l) {
        k_gather<<<(NN + 3) / 4, 256, 0, stream>>>(row_ptr, col, A2, inv);
        k_gemm<<<(NN + 63) / 64, 256, 0, stream>>>(
            A2, A2, Wfrag + (size_t)l * 32768,
            bconv + l * CC, bng + l * CC, bnb + l * CC, bnm + l * CC, bnv + l * CC,
            x, (l == 0) ? 1 : 0);
    }
    k_head<<<NN / 4, 256, 0, stream>>>(A2, lng, lnb, W1, b1,
                                       bog, bob, bom, bov, W2, b2, (float*)d_out);
}

// Round 8
// 725.304 us; speedup vs baseline: 15.6533x; 1.1052x over previous
//
#include <hip/hip_runtime.h>

#define NN 100000
#define EE 1600000
#define CC 128
#define EPS 1e-5f

typedef __attribute__((ext_vector_type(8))) short sh8;
typedef __attribute__((ext_vector_type(4))) float fl4;

static __device__ __forceinline__ unsigned short f2bf(float f) {
    unsigned u = __float_as_uint(f);
    u = (u + 0x7fff + ((u >> 16) & 1)) >> 16;   // round-to-nearest-even
    return (unsigned short)u;
}
static __device__ __forceinline__ float bf2f(unsigned short s) {
    return __uint_as_float((unsigned)s << 16);
}

// ---------- CSR build ----------
__global__ __launch_bounds__(256) void k_count(const int* __restrict__ ei,
                                               int* __restrict__ cnt) {
    int e = blockIdx.x * 256 + threadIdx.x;
    if (e < EE) atomicAdd(&cnt[ei[EE + e]], 1);
}

// single-block exclusive scan over cnt -> row_ptr, plus inv = 1/max(cnt,1)
// (round-3 validated version, 1 element/thread)
__global__ __launch_bounds__(1024) void k_scan(const int* __restrict__ cnt,
                                               int* __restrict__ row_ptr,
                                               float* __restrict__ inv) {
    __shared__ int wsum[16];
    __shared__ int cbase;
    const int t = threadIdx.x;
    if (t == 0) cbase = 0;
    __syncthreads();
    for (int base = 0; base < NN; base += 1024) {
        int i = base + t;
        int v = (i < NN) ? cnt[i] : 0;
        int lane = t & 63, w = t >> 6;
        int s = v;
#pragma unroll
        for (int o = 1; o < 64; o <<= 1) {
            int u = __shfl_up(s, o);
            if (lane >= o) s += u;
        }
        if (lane == 63) wsum[w] = s;
        __syncthreads();
        if (t < 16) {
            int ws = wsum[t];
#pragma unroll
            for (int o = 1; o < 16; o <<= 1) {
                int u = __shfl_up(ws, o);
                if (t >= o) ws += u;
            }
            wsum[t] = ws;
        }
        __syncthreads();
        int excl = cbase + (w ? wsum[w - 1] : 0) + (s - v);
        if (i < NN) {
            row_ptr[i] = excl;
            inv[i] = 1.0f / fmaxf((float)v, 1.0f);
        }
        __syncthreads();
        if (t == 0) cbase += wsum[15];
        __syncthreads();
    }
    if (t == 0) row_ptr[NN] = cbase;
}

__global__ __launch_bounds__(256) void k_fill(const int* __restrict__ ei,
                                              const int* __restrict__ row_ptr,
                                              int* __restrict__ fill,
                                              int* __restrict__ col) {
    int e = blockIdx.x * 256 + threadIdx.x;
    if (e < EE) {
        int d = ei[EE + e];
        int pos = row_ptr[d] + atomicAdd(&fill[d], 1);
        col[pos] = ei[e];
    }
}

// ---------- x fp32 -> A2 h-columns bf16 ----------
__global__ __launch_bounds__(256) void k_cvtx(const float* __restrict__ x,
                                              unsigned short* __restrict__ A2) {
    int id = blockIdx.x * 256 + threadIdx.x;
    if (id >= NN * CC / 8) return;
    int row = id >> 4, g = id & 15;
    const float* xp = x + (size_t)row * CC + g * 8;
    unsigned short o[8];
#pragma unroll
    for (int e = 0; e < 8; ++e) o[e] = f2bf(xp[e]);
    *(sh8*)(A2 + (size_t)row * 256 + 128 + g * 8) = *(sh8*)o;
}

// ---------- build Wfrag (layers): [lay][ks][nt][lane][8] ----------
__global__ __launch_bounds__(256) void k_wcvt(const float* __restrict__ Wl,
                                              const float* __restrict__ Wr,
                                              unsigned short* __restrict__ Wfrag) {
    int id = blockIdx.x * 256 + threadIdx.x;   // 16384
    if (id >= 16384) return;
    int lay = id >> 12;
    int rem = id & 4095;
    int ks = rem >> 9;
    int nt = (rem >> 6) & 7;
    int l = rem & 63;
    int c = nt * 16 + (l & 15);
    int kb = ks * 32 + (l >> 4) * 8;
    const float* WL = Wl + (size_t)lay * CC * CC;
    const float* WR = Wr + (size_t)lay * CC * CC;
    unsigned short o[8];
#pragma unroll
    for (int e = 0; e < 8; ++e) {
        int k = kb + e;
        float v = (k < 128) ? WL[(size_t)k * CC + c] : WR[(size_t)(k - 128) * CC + c];
        o[e] = f2bf(v);
    }
    *(sh8*)(Wfrag + (size_t)lay * 32768 + ks * 4096 + nt * 512 + l * 8) = *(sh8*)o;
}

// ---------- gather-mean (bf16): wave per node, 4-way edge ILP ----------
__global__ __launch_bounds__(256) void k_gather(const int* __restrict__ row_ptr,
                                                const int* __restrict__ col,
                                                unsigned short* __restrict__ A2,
                                                const float* __restrict__ inv) {
    int node = blockIdx.x * 4 + (threadIdx.x >> 6);
    if (node >= NN) return;
    int lane = threadIdx.x & 63;
    int g = lane & 15;
    int par = lane >> 4;
    const unsigned short* hbase = A2 + 128 + g * 8;
    int beg = row_ptr[node], end = row_ptr[node + 1];
    float acc[8];
#pragma unroll
    for (int e = 0; e < 8; ++e) acc[e] = 0.f;
    for (int j = beg + par; j < end; j += 4) {
        int s = col[j];
        sh8 v = *(const sh8*)(hbase + (size_t)s * 256);
#pragma unroll
        for (int e = 0; e < 8; ++e) acc[e] += bf2f((unsigned short)v[e]);
    }
#pragma unroll
    for (int e = 0; e < 8; ++e) {
        acc[e] += __shfl_xor(acc[e], 16);
        acc[e] += __shfl_xor(acc[e], 32);
    }
    if (par == 0) {
        float sc = inv[node];
        unsigned short o[8];
#pragma unroll
        for (int e = 0; e < 8; ++e) o[e] = f2bf(acc[e] * sc);
        *(sh8*)(A2 + (size_t)node * 256 + g * 8) = *(sh8*)o;
    }
}

// ---------- MFMA GEMM: A2 @ Wfrag -> BN+ReLU(+x) -> A2 h-cols ----------
__global__ __launch_bounds__(256) void k_gemm(
    const unsigned short* __restrict__ A2w,
    unsigned short* __restrict__ A2,
    const unsigned short* __restrict__ Wfrag,
    const float* __restrict__ bconv,
    const float* __restrict__ bng, const float* __restrict__ bnb,
    const float* __restrict__ bnm, const float* __restrict__ bnv,
    const float* __restrict__ x, int add_res)
{
    const int t = threadIdx.x;
    const int w = t >> 6, l = t & 63;
    const int rowbase = blockIdx.x * 64 + w * 16;
    int r_a = rowbase + (l & 15);
    if (r_a >= NN) r_a = NN - 1;
    const unsigned short* arow = A2w + (size_t)r_a * 256 + (l >> 4) * 8;

    fl4 acc[8];
#pragma unroll
    for (int nt = 0; nt < 8; ++nt) acc[nt] = (fl4){0.f, 0.f, 0.f, 0.f};

#pragma unroll
    for (int ks = 0; ks < 8; ++ks) {
        sh8 a = *(const sh8*)(arow + ks * 32);
        const unsigned short* wk = Wfrag + ks * 4096 + l * 8;
#pragma unroll
        for (int nt = 0; nt < 8; ++nt) {
            sh8 b = *(const sh8*)(wk + nt * 512);
            acc[nt] = __builtin_amdgcn_mfma_f32_16x16x32_bf16(a, b, acc[nt], 0, 0, 0);
        }
    }

    const int r0 = rowbase + (l >> 4) * 4;
#pragma unroll
    for (int nt = 0; nt < 8; ++nt) {
        int c = nt * 16 + (l & 15);
        float sc = bng[c] * rsqrtf(bnv[c] + EPS);
        float tt = (bconv[c] - bnm[c]) * sc + bnb[c];
#pragma unroll
        for (int j = 0; j < 4; ++j) {
            int row = r0 + j;
            if (row < NN) {
                float v = acc[nt][j] * sc + tt;
                v = fmaxf(v, 0.f);
                if (add_res) v += x[(size_t)row * CC + c];
                A2[(size_t)row * 256 + 128 + c] = f2bf(v);
            }
        }
    }
}

// ---------- fused LN + fp32 tiled GEMM head: 32 nodes/block ----------
// Phase A: round-3 LN pattern per wave (8 nodes each) -> hs fp32.
// Phase B: round-1 tile-GEMM pattern: thread = 2 rows x 4 cols, K=128 via float4.
// Phase C: BN-out + ReLU + W2 dot, shfl_xor(1,2,4,8) over the 16-lane col group.
__global__ __launch_bounds__(256) void k_head2(
    const unsigned short* __restrict__ A2,
    const float* __restrict__ lng, const float* __restrict__ lnb,
    const float* __restrict__ W1, const float* __restrict__ b1,
    const float* __restrict__ bog, const float* __restrict__ bob,
    const float* __restrict__ bom, const float* __restrict__ bov,
    const float* __restrict__ W2, const float* __restrict__ b2,
    float* __restrict__ out)
{
    __shared__ float Ws[128][68];   // W1 [k][n], padded
    __shared__ float hs[32][132];   // LN-normalized rows, padded
    const int t = threadIdx.x;
    const int nbase = blockIdx.x * 32;   // NN % 32 == 0 -> no tail guards

    // stage W1: 8192 floats = 2048 float4, 8 per thread
#pragma unroll
    for (int i = 0; i < 8; ++i) {
        int fi = (t + i * 256) * 4;
        int k = fi >> 6, j = fi & 63;
        *(float4*)&Ws[k][j] = *(const float4*)(W1 + fi);
    }

    // LN: wave wv handles nodes nbase + wv*8 .. +7
    const int lane = t & 63, wv = t >> 6;
#pragma unroll
    for (int i = 0; i < 8; ++i) {
        int nl = wv * 8 + i;
        const unsigned short* hp = A2 + (size_t)(nbase + nl) * 256 + 128;
        float v0 = bf2f(hp[lane]), v1 = bf2f(hp[lane + 64]);
        float s1 = v0 + v1, s2 = v0 * v0 + v1 * v1;
#pragma unroll
        for (int o = 32; o >= 1; o >>= 1) {
            s1 += __shfl_xor(s1, o);
            s2 += __shfl_xor(s2, o);
        }
        float mean = s1 * (1.0f / 128.0f);
        float var = s2 * (1.0f / 128.0f) - mean * mean;
        float rstd = rsqrtf(var + EPS);
        hs[nl][lane] = (v0 - mean) * rstd * lng[lane] + lnb[lane];
        hs[nl][lane + 64] = (v1 - mean) * rstd * lng[lane + 64] + lnb[lane + 64];
    }
    __syncthreads();

    // GEMM: thread (tx = t&15 -> cols tx*4..+3, ty = t>>4 -> rows ty*2..+1)
    const int tx = t & 15, ty = t >> 4;
    const int c0 = tx * 4, r0 = ty * 2;
    float acc[2][4] = {{0.f, 0.f, 0.f, 0.f}, {0.f, 0.f, 0.f, 0.f}};
#pragma unroll 4
    for (int k = 0; k < 128; k += 4) {
        float4 w0 = *(const float4*)&Ws[k][c0];
        float4 w1 = *(const float4*)&Ws[k + 1][c0];
        float4 w2v = *(const float4*)&Ws[k + 2][c0];
        float4 w3 = *(const float4*)&Ws[k + 3][c0];
#pragma unroll
        for (int i = 0; i < 2; ++i) {
            float4 a = *(const float4*)&hs[r0 + i][k];
            acc[i][0] += a.x * w0.x + a.y * w1.x + a.z * w2v.x + a.w * w3.x;
            acc[i][1] += a.x * w0.y + a.y * w1.y + a.z * w2v.y + a.w * w3.y;
            acc[i][2] += a.x * w0.z + a.y * w1.z + a.z * w2v.z + a.w * w3.z;
            acc[i][3] += a.x * w0.w + a.y * w1.w + a.z * w2v.w + a.w * w3.w;
        }
    }

    // epilogue: +b1, BN(out), ReLU, dot W2, reduce over tx
    float rr[2] = {0.f, 0.f};
#pragma unroll
    for (int jc = 0; jc < 4; ++jc) {
        int c = c0 + jc;
        float sc = bog[c] * rsqrtf(bov[c] + EPS);
        float tt = (b1[c] - bom[c]) * sc + bob[c];
        float w2 = W2[c];
#pragma unroll
        for (int i = 0; i < 2; ++i) {
            float v = acc[i][jc] * sc + tt;
            v = fmaxf(v, 0.f);
            rr[i] += v * w2;
        }
    }
#pragma unroll
    for (int i = 0; i < 2; ++i) {
        rr[i] += __shfl_xor(rr[i], 1);
        rr[i] += __shfl_xor(rr[i], 2);
        rr[i] += __shfl_xor(rr[i], 4);
        rr[i] += __shfl_xor(rr[i], 8);
    }
    if (tx == 0) {
        float bb = b2[0];
        out[nbase + r0] = rr[0] + bb;
        out[nbase + r0 + 1] = rr[1] + bb;
    }
}

extern "C" void kernel_launch(void* const* d_in, const int* in_sizes, int n_in,
                              void* d_out, int out_size, void* d_ws, size_t ws_size,
                              hipStream_t stream) {
    const float* x     = (const float*)d_in[0];
    const int*   ei    = (const int*)d_in[1];
    const float* Wl    = (const float*)d_in[2];
    const float* Wr    = (const float*)d_in[3];
    const float* bconv = (const float*)d_in[4];
    const float* bng   = (const float*)d_in[5];
    const float* bnb   = (const float*)d_in[6];
    const float* bnm   = (const float*)d_in[7];
    const float* bnv   = (const float*)d_in[8];
    const float* lng   = (const float*)d_in[9];
    const float* lnb   = (const float*)d_in[10];
    const float* W1    = (const float*)d_in[11];
    const float* b1    = (const float*)d_in[12];
    const float* bog   = (const float*)d_in[13];
    const float* bob   = (const float*)d_in[14];
    const float* bom   = (const float*)d_in[15];
    const float* bov   = (const float*)d_in[16];
    const float* W2    = (const float*)d_in[17];
    const float* b2    = (const float*)d_in[18];

    unsigned short* A2     = (unsigned short*)d_ws;           // N*256
    unsigned short* Wfrag  = A2 + (size_t)NN * 256;           // 4*32768
    float* inv     = (float*)(Wfrag + 4 * 32768);             // N
    int*   cnt     = (int*)(inv + NN);                        // N
    int*   fill    = cnt + NN;                                // N (adjacent -> one memset)
    int*   row_ptr = fill + NN;                               // N+1
    int*   col     = row_ptr + NN + 1;                        // E

    hipMemsetAsync(cnt, 0, 2 * NN * sizeof(int), stream);
    k_cvtx<<<(NN * CC / 8 + 255) / 256, 256, 0, stream>>>(x, A2);
    k_wcvt<<<64, 256, 0, stream>>>(Wl, Wr, Wfrag);
    k_count<<<(EE + 255) / 256, 256, 0, stream>>>(ei, cnt);
    k_scan<<<1, 1024, 0, stream>>>(cnt, row_ptr, inv);
    k_fill<<<(EE + 255) / 256, 256, 0, stream>>>(ei, row_ptr, fill, col);

    for (int l = 0; l < 4; ++l) {
        k_gather<<<(NN + 3) / 4, 256, 0, stream>>>(row_ptr, col, A2, inv);
        k_gemm<<<(NN + 63) / 64, 256, 0, stream>>>(
            A2, A2, Wfrag + (size_t)l * 32768,
            bconv + l * CC, bng + l * CC, bnb + l * CC, bnm + l * CC, bnv + l * CC,
            x, (l == 0) ? 1 : 0);
    }
    k_head2<<<NN / 32, 256, 0, stream>>>(A2, lng, lnb, W1, b1,
                                         bog, bob, bom, bov, W2, b2, (float*)d_out);
}

// Round 9
// 663.407 us; speedup vs baseline: 17.1138x; 1.0933x over previous
//
#include <hip/hip_runtime.h>

#define NN 100000
#define EE 1600000
#define CC 128
#define EPS 1e-5f
#define NBLK ((NN + 1023) >> 10)   // 98 scan blocks

typedef __attribute__((ext_vector_type(8))) short sh8;
typedef __attribute__((ext_vector_type(4))) float fl4;

static __device__ __forceinline__ unsigned short f2bf(float f) {
    unsigned u = __float_as_uint(f);
    u = (u + 0x7fff + ((u >> 16) & 1)) >> 16;   // round-to-nearest-even
    return (unsigned short)u;
}
static __device__ __forceinline__ float bf2f(unsigned short s) {
    return __uint_as_float((unsigned)s << 16);
}

// ---------- CSR build ----------
__global__ __launch_bounds__(256) void k_count(const int* __restrict__ ei,
                                               int* __restrict__ cnt) {
    int e = blockIdx.x * 256 + threadIdx.x;
    if (e < EE) atomicAdd(&cnt[ei[EE + e]], 1);
}

// block partial sums of cnt (1024 elems/block)
__global__ __launch_bounds__(1024) void k_bsum(const int* __restrict__ cnt,
                                               int* __restrict__ bsum) {
    __shared__ int wsum[16];
    const int t = threadIdx.x;
    int i = blockIdx.x * 1024 + t;
    int v = (i < NN) ? cnt[i] : 0;
#pragma unroll
    for (int o = 1; o < 64; o <<= 1) v += __shfl_xor(v, o);
    if ((t & 63) == 0) wsum[t >> 6] = v;
    __syncthreads();
    if (t == 0) {
        int s = 0;
#pragma unroll
        for (int i2 = 0; i2 < 16; ++i2) s += wsum[i2];
        bsum[blockIdx.x] = s;
    }
}

// scan the 98 block sums (single small block, 2 waves)
__global__ __launch_bounds__(128) void k_bscan(const int* __restrict__ bsum,
                                               int* __restrict__ boff,
                                               int* __restrict__ row_ptr) {
    __shared__ int wsum2[2];
    const int t = threadIdx.x;
    int v = (t < NBLK) ? bsum[t] : 0;
    int lane = t & 63, w = t >> 6;
    int s = v;
#pragma unroll
    for (int o = 1; o < 64; o <<= 1) {
        int u = __shfl_up(s, o);
        if (lane >= o) s += u;
    }
    if (lane == 63) wsum2[w] = s;
    __syncthreads();
    int excl = (w ? wsum2[0] : 0) + (s - v);
    if (t < NBLK) boff[t] = excl;
    if (t == NBLK - 1) row_ptr[NN] = excl + v;
}

// per-block re-scan + add block offset; writes row_ptr, fill(seed), inv
// (inner scan is the round-3-validated butterfly pattern)
__global__ __launch_bounds__(1024) void k_rescan(const int* __restrict__ cnt,
                                                 const int* __restrict__ boff,
                                                 int* __restrict__ row_ptr,
                                                 int* __restrict__ fill,
                                                 float* __restrict__ inv) {
    __shared__ int wsum[16];
    const int t = threadIdx.x;
    int i = blockIdx.x * 1024 + t;
    int v = (i < NN) ? cnt[i] : 0;
    int lane = t & 63, w = t >> 6;
    int s = v;
#pragma unroll
    for (int o = 1; o < 64; o <<= 1) {
        int u = __shfl_up(s, o);
        if (lane >= o) s += u;
    }
    if (lane == 63) wsum[w] = s;
    __syncthreads();
    if (t < 16) {
        int ws = wsum[t];
#pragma unroll
        for (int o = 1; o < 16; o <<= 1) {
            int u = __shfl_up(ws, o);
            if (t >= o) ws += u;
        }
        wsum[t] = ws;
    }
    __syncthreads();
    int excl = boff[blockIdx.x] + (w ? wsum[w - 1] : 0) + (s - v);
    if (i < NN) {
        row_ptr[i] = excl;
        fill[i] = excl;
        inv[i] = 1.0f / fmaxf((float)v, 1.0f);
    }
}

// fill: pos directly from pre-seeded fill counters (no row_ptr read)
__global__ __launch_bounds__(256) void k_fill2(const int* __restrict__ ei,
                                               int* __restrict__ fill,
                                               int* __restrict__ col) {
    int e = blockIdx.x * 256 + threadIdx.x;
    if (e < EE) {
        int pos = atomicAdd(&fill[ei[EE + e]], 1);
        col[pos] = ei[e];
    }
}

// ---------- x fp32 -> A2 h-columns bf16 ----------
__global__ __launch_bounds__(256) void k_cvtx(const float* __restrict__ x,
                                              unsigned short* __restrict__ A2) {
    int id = blockIdx.x * 256 + threadIdx.x;
    if (id >= NN * CC / 8) return;
    int row = id >> 4, g = id & 15;
    const float* xp = x + (size_t)row * CC + g * 8;
    unsigned short o[8];
#pragma unroll
    for (int e = 0; e < 8; ++e) o[e] = f2bf(xp[e]);
    *(sh8*)(A2 + (size_t)row * 256 + 128 + g * 8) = *(sh8*)o;
}

// ---------- build Wfrag (layers): [lay][ks][nt][lane][8] ----------
__global__ __launch_bounds__(256) void k_wcvt(const float* __restrict__ Wl,
                                              const float* __restrict__ Wr,
                                              unsigned short* __restrict__ Wfrag) {
    int id = blockIdx.x * 256 + threadIdx.x;   // 16384
    if (id >= 16384) return;
    int lay = id >> 12;
    int rem = id & 4095;
    int ks = rem >> 9;
    int nt = (rem >> 6) & 7;
    int l = rem & 63;
    int c = nt * 16 + (l & 15);
    int kb = ks * 32 + (l >> 4) * 8;
    const float* WL = Wl + (size_t)lay * CC * CC;
    const float* WR = Wr + (size_t)lay * CC * CC;
    unsigned short o[8];
#pragma unroll
    for (int e = 0; e < 8; ++e) {
        int k = kb + e;
        float v = (k < 128) ? WL[(size_t)k * CC + c] : WR[(size_t)(k - 128) * CC + c];
        o[e] = f2bf(v);
    }
    *(sh8*)(Wfrag + (size_t)lay * 32768 + ks * 4096 + nt * 512 + l * 8) = *(sh8*)o;
}

// ---------- gather-mean (bf16): wave per node, 4-way edge ILP ----------
__global__ __launch_bounds__(256) void k_gather(const int* __restrict__ row_ptr,
                                                const int* __restrict__ col,
                                                unsigned short* __restrict__ A2,
                                                const float* __restrict__ inv) {
    int node = blockIdx.x * 4 + (threadIdx.x >> 6);
    if (node >= NN) return;
    int lane = threadIdx.x & 63;
    int g = lane & 15;
    int par = lane >> 4;
    const unsigned short* hbase = A2 + 128 + g * 8;
    int beg = row_ptr[node], end = row_ptr[node + 1];
    float acc[8];
#pragma unroll
    for (int e = 0; e < 8; ++e) acc[e] = 0.f;
    for (int j = beg + par; j < end; j += 4) {
        int s = col[j];
        sh8 v = *(const sh8*)(hbase + (size_t)s * 256);
#pragma unroll
        for (int e = 0; e < 8; ++e) acc[e] += bf2f((unsigned short)v[e]);
    }
#pragma unroll
    for (int e = 0; e < 8; ++e) {
        acc[e] += __shfl_xor(acc[e], 16);
        acc[e] += __shfl_xor(acc[e], 32);
    }
    if (par == 0) {
        float sc = inv[node];
        unsigned short o[8];
#pragma unroll
        for (int e = 0; e < 8; ++e) o[e] = f2bf(acc[e] * sc);
        *(sh8*)(A2 + (size_t)node * 256 + g * 8) = *(sh8*)o;
    }
}

// ---------- MFMA GEMM: A2 @ Wfrag -> BN+ReLU(+x) -> A2 h-cols ----------
__global__ __launch_bounds__(256) void k_gemm(
    const unsigned short* __restrict__ A2w,
    unsigned short* __restrict__ A2,
    const unsigned short* __restrict__ Wfrag,
    const float* __restrict__ bconv,
    const float* __restrict__ bng, const float* __restrict__ bnb,
    const float* __restrict__ bnm, const float* __restrict__ bnv,
    const float* __restrict__ x, int add_res)
{
    const int t = threadIdx.x;
    const int w = t >> 6, l = t & 63;
    const int rowbase = blockIdx.x * 64 + w * 16;
    int r_a = rowbase + (l & 15);
    if (r_a >= NN) r_a = NN - 1;
    const unsigned short* arow = A2w + (size_t)r_a * 256 + (l >> 4) * 8;

    fl4 acc[8];
#pragma unroll
    for (int nt = 0; nt < 8; ++nt) acc[nt] = (fl4){0.f, 0.f, 0.f, 0.f};

#pragma unroll
    for (int ks = 0; ks < 8; ++ks) {
        sh8 a = *(const sh8*)(arow + ks * 32);
        const unsigned short* wk = Wfrag + ks * 4096 + l * 8;
#pragma unroll
        for (int nt = 0; nt < 8; ++nt) {
            sh8 b = *(const sh8*)(wk + nt * 512);
            acc[nt] = __builtin_amdgcn_mfma_f32_16x16x32_bf16(a, b, acc[nt], 0, 0, 0);
        }
    }

    const int r0 = rowbase + (l >> 4) * 4;
#pragma unroll
    for (int nt = 0; nt < 8; ++nt) {
        int c = nt * 16 + (l & 15);
        float sc = bng[c] * rsqrtf(bnv[c] + EPS);
        float tt = (bconv[c] - bnm[c]) * sc + bnb[c];
#pragma unroll
        for (int j = 0; j < 4; ++j) {
            int row = r0 + j;
            if (row < NN) {
                float v = acc[nt][j] * sc + tt;
                v = fmaxf(v, 0.f);
                if (add_res) v += x[(size_t)row * CC + c];
                A2[(size_t)row * 256 + 128 + c] = f2bf(v);
            }
        }
    }
}

// ---------- fused LN + fp32 tiled GEMM head: 32 nodes/block ----------
__global__ __launch_bounds__(256) void k_head2(
    const unsigned short* __restrict__ A2,
    const float* __restrict__ lng, const float* __restrict__ lnb,
    const float* __restrict__ W1, const float* __restrict__ b1,
    const float* __restrict__ bog, const float* __restrict__ bob,
    const float* __restrict__ bom, const float* __restrict__ bov,
    const float* __restrict__ W2, const float* __restrict__ b2,
    float* __restrict__ out)
{
    __shared__ float Ws[128][68];   // W1 [k][n], padded
    __shared__ float hs[32][132];   // LN-normalized rows, padded
    const int t = threadIdx.x;
    const int nbase = blockIdx.x * 32;   // NN % 32 == 0 -> no tail guards

#pragma unroll
    for (int i = 0; i < 8; ++i) {
        int fi = (t + i * 256) * 4;
        int k = fi >> 6, j = fi & 63;
        *(float4*)&Ws[k][j] = *(const float4*)(W1 + fi);
    }

    const int lane = t & 63, wv = t >> 6;
#pragma unroll
    for (int i = 0; i < 8; ++i) {
        int nl = wv * 8 + i;
        const unsigned short* hp = A2 + (size_t)(nbase + nl) * 256 + 128;
        float v0 = bf2f(hp[lane]), v1 = bf2f(hp[lane + 64]);
        float s1 = v0 + v1, s2 = v0 * v0 + v1 * v1;
#pragma unroll
        for (int o = 32; o >= 1; o >>= 1) {
            s1 += __shfl_xor(s1, o);
            s2 += __shfl_xor(s2, o);
        }
        float mean = s1 * (1.0f / 128.0f);
        float var = s2 * (1.0f / 128.0f) - mean * mean;
        float rstd = rsqrtf(var + EPS);
        hs[nl][lane] = (v0 - mean) * rstd * lng[lane] + lnb[lane];
        hs[nl][lane + 64] = (v1 - mean) * rstd * lng[lane + 64] + lnb[lane + 64];
    }
    __syncthreads();

    const int tx = t & 15, ty = t >> 4;
    const int c0 = tx * 4, r0 = ty * 2;
    float acc[2][4] = {{0.f, 0.f, 0.f, 0.f}, {0.f, 0.f, 0.f, 0.f}};
#pragma unroll 4
    for (int k = 0; k < 128; k += 4) {
        float4 w0 = *(const float4*)&Ws[k][c0];
        float4 w1 = *(const float4*)&Ws[k + 1][c0];
        float4 w2v = *(const float4*)&Ws[k + 2][c0];
        float4 w3 = *(const float4*)&Ws[k + 3][c0];
#pragma unroll
        for (int i = 0; i < 2; ++i) {
            float4 a = *(const float4*)&hs[r0 + i][k];
            acc[i][0] += a.x * w0.x + a.y * w1.x + a.z * w2v.x + a.w * w3.x;
            acc[i][1] += a.x * w0.y + a.y * w1.y + a.z * w2v.y + a.w * w3.y;
            acc[i][2] += a.x * w0.z + a.y * w1.z + a.z * w2v.z + a.w * w3.z;
            acc[i][3] += a.x * w0.w + a.y * w1.w + a.z * w2v.w + a.w * w3.w;
        }
    }

    float rr[2] = {0.f, 0.f};
#pragma unroll
    for (int jc = 0; jc < 4; ++jc) {
        int c = c0 + jc;
        float sc = bog[c] * rsqrtf(bov[c] + EPS);
        float tt = (b1[c] - bom[c]) * sc + bob[c];
        float w2 = W2[c];
#pragma unroll
        for (int i = 0; i < 2; ++i) {
            float v = acc[i][jc] * sc + tt;
            v = fmaxf(v, 0.f);
            rr[i] += v * w2;
        }
    }
#pragma unroll
    for (int i = 0; i < 2; ++i) {
        rr[i] += __shfl_xor(rr[i], 1);
        rr[i] += __shfl_xor(rr[i], 2);
        rr[i] += __shfl_xor(rr[i], 4);
        rr[i] += __shfl_xor(rr[i], 8);
    }
    if (tx == 0) {
        float bb = b2[0];
        out[nbase + r0] = rr[0] + bb;
        out[nbase + r0 + 1] = rr[1] + bb;
    }
}

extern "C" void kernel_launch(void* const* d_in, const int* in_sizes, int n_in,
                              void* d_out, int out_size, void* d_ws, size_t ws_size,
                              hipStream_t stream) {
    const float* x     = (const float*)d_in[0];
    const int*   ei    = (const int*)d_in[1];
    const float* Wl    = (const float*)d_in[2];
    const float* Wr    = (const float*)d_in[3];
    const float* bconv = (const float*)d_in[4];
    const float* bng   = (const float*)d_in[5];
    const float* bnb   = (const float*)d_in[6];
    const float* bnm   = (const float*)d_in[7];
    const float* bnv   = (const float*)d_in[8];
    const float* lng   = (const float*)d_in[9];
    const float* lnb   = (const float*)d_in[10];
    const float* W1    = (const float*)d_in[11];
    const float* b1    = (const float*)d_in[12];
    const float* bog   = (const float*)d_in[13];
    const float* bob   = (const float*)d_in[14];
    const float* bom   = (const float*)d_in[15];
    const float* bov   = (const float*)d_in[16];
    const float* W2    = (const float*)d_in[17];
    const float* b2    = (const float*)d_in[18];

    unsigned short* A2     = (unsigned short*)d_ws;           // N*256
    unsigned short* Wfrag  = A2 + (size_t)NN * 256;           // 4*32768
    float* inv     = (float*)(Wfrag + 4 * 32768);             // N
    int*   cnt     = (int*)(inv + NN);                        // N
    int*   fill    = cnt + NN;                                // N
    int*   row_ptr = fill + NN;                               // N+1
    int*   col     = row_ptr + NN + 1;                        // E
    int*   bsum    = col + EE;                                // NBLK
    int*   boff    = bsum + NBLK;                             // NBLK

    hipMemsetAsync(cnt, 0, NN * sizeof(int), stream);
    k_cvtx<<<(NN * CC / 8 + 255) / 256, 256, 0, stream>>>(x, A2);
    k_wcvt<<<64, 256, 0, stream>>>(Wl, Wr, Wfrag);
    k_count<<<(EE + 255) / 256, 256, 0, stream>>>(ei, cnt);
    k_bsum<<<NBLK, 1024, 0, stream>>>(cnt, bsum);
    k_bscan<<<1, 128, 0, stream>>>(bsum, boff, row_ptr);
    k_rescan<<<NBLK, 1024, 0, stream>>>(cnt, boff, row_ptr, fill, inv);
    k_fill2<<<(EE + 255) / 256, 256, 0, stream>>>(ei, fill, col);

    for (int l = 0; l < 4; ++l) {
        k_gather<<<(NN + 3) / 4, 256, 0, stream>>>(row_ptr, col, A2, inv);
        k_gemm<<<(NN + 63) / 64, 256, 0, stream>>>(
            A2, A2, Wfrag + (size_t)l * 32768,
            bconv + l * CC, bng + l * CC, bnb + l * CC, bnm + l * CC, bnv + l * CC,
            x, (l == 0) ? 1 : 0);
    }
    k_head2<<<NN / 32, 256, 0, stream>>>(A2, lng, lnb, W1, b1,
                                         bog, bob, bom, bov, W2, b2, (float*)d_out);
}